// Round 2
// baseline (711.207 us; speedup 1.0000x reference)
//
#include <hip/hip_runtime.h>
#include <hip/hip_bf16.h>
#include <stdint.h>

#define IN_F 4096
#define OUT_F 4096
#define NOUT 40
#define KPAD 4160   // 4096 + 64 (40 outlier cols + 24 zero pad) = 65 * 64
#define M_TOT 8192  // 4*2048

#define BM 256
#define BN 256
#define BK 64
#define KTILES 65   // KPAD / BK
#define ABS_BLOCKS 2048

typedef float f32x4 __attribute__((ext_vector_type(4)));
typedef __bf16 bf16x8 __attribute__((ext_vector_type(8)));

typedef __attribute__((address_space(1))) void GV;
typedef __attribute__((address_space(3))) void LV;
#define GLDS16(gp, lp) \
  __builtin_amdgcn_global_load_lds((GV*)(gp), (LV*)(lp), 16, 0, 0)

__device__ __forceinline__ unsigned short f2bf(float f) {
  unsigned u = __float_as_uint(f);
  u += 0x7FFFu + ((u >> 16) & 1u);
  return (unsigned short)(u >> 16);
}

// ---- fused: masked global abs-max over x  ||  W' = [W | B | 0] bf16 prep ----
// blocks [0, ABS_BLOCKS): absmax; blocks [ABS_BLOCKS, ABS_BLOCKS+OUT_F): prep_w.
__global__ void k_absmax_prepw(const float4* __restrict__ x4,
                               const int* __restrict__ oidx,
                               unsigned* __restrict__ out,
                               const float* __restrict__ w,
                               const float* __restrict__ Bm,
                               unsigned short* __restrict__ W) {
  __shared__ unsigned bits[128];
  const int t = threadIdx.x;
  if ((int)blockIdx.x < ABS_BLOCKS) {
    if (t < 128) bits[t] = 0;
    __syncthreads();
    if (t < NOUT) {
      int c = oidx[t];
      atomicOr(&bits[c >> 5], 1u << (c & 31));
    }
    __syncthreads();
    const int n4 = M_TOT * IN_F / 4;
    float m = 0.f;
    const int stride = ABS_BLOCKS * 256;
    for (int i = blockIdx.x * 256 + t; i < n4; i += stride) {
      float4 u = x4[i];
      unsigned wb = bits[(i & 1023) >> 3];
      int sh = (i & 7) * 4;
      m = fmaxf(m, ((wb >> (sh + 0)) & 1) ? 0.f : fabsf(u.x));
      m = fmaxf(m, ((wb >> (sh + 1)) & 1) ? 0.f : fabsf(u.y));
      m = fmaxf(m, ((wb >> (sh + 2)) & 1) ? 0.f : fabsf(u.z));
      m = fmaxf(m, ((wb >> (sh + 3)) & 1) ? 0.f : fabsf(u.w));
    }
#pragma unroll
    for (int off = 32; off; off >>= 1) m = fmaxf(m, __shfl_down(m, off, 64));
    if ((t & 63) == 0) atomicMax(out, __float_as_uint(m));
  } else {
    const int o = (int)blockIdx.x - ABS_BLOCKS;
    const float4* wr = (const float4*)(w + (size_t)o * IN_F);
    uint4* Wr = (uint4*)(W + (size_t)o * KPAD);
#pragma unroll
    for (int rep = 0; rep < 2; ++rep) {
      const int c = t + rep * 256;
      float4 u0 = wr[2 * c];
      float4 u1 = wr[2 * c + 1];
      uint4 ov;
      ov.x = (unsigned)f2bf(u0.x) | ((unsigned)f2bf(u0.y) << 16);
      ov.y = (unsigned)f2bf(u0.z) | ((unsigned)f2bf(u0.w) << 16);
      ov.z = (unsigned)f2bf(u1.x) | ((unsigned)f2bf(u1.y) << 16);
      ov.w = (unsigned)f2bf(u1.z) | ((unsigned)f2bf(u1.w) << 16);
      Wr[c] = ov;
    }
    if (t < 64)
      W[(size_t)o * KPAD + IN_F + t] =
          (t < NOUT) ? f2bf(Bm[(size_t)o * NOUT + t]) : (unsigned short)0;
  }
}

// ---- A' = [rint(clip(x)*127/upper) | (x - clip(x))*127/upper on outlier cols | 0] ----
__global__ void k_prep_a(const float* __restrict__ x,
                         const int* __restrict__ oidx,
                         const unsigned* __restrict__ upper_bits,
                         unsigned short* __restrict__ A) {
  const int m = blockIdx.x;
  const int t = threadIdx.x;
  const float upper = __uint_as_float(*upper_bits);
  const float inv = 127.0f / fmaxf(upper, 1e-5f);
  const float4* xr = (const float4*)(x + (size_t)m * IN_F);
  uint4* Ar = (uint4*)(A + (size_t)m * KPAD);
#pragma unroll
  for (int rep = 0; rep < 2; ++rep) {
    const int c = t + rep * 256;
    float4 u0 = xr[2 * c];
    float4 u1 = xr[2 * c + 1];
    float f[8] = {u0.x, u0.y, u0.z, u0.w, u1.x, u1.y, u1.z, u1.w};
    unsigned o[4];
#pragma unroll
    for (int w = 0; w < 4; ++w) {
      float a = fminf(fmaxf(f[2 * w], -upper), upper);
      float b = fminf(fmaxf(f[2 * w + 1], -upper), upper);
      unsigned short b0 = f2bf(rintf(a * inv));
      unsigned short b1 = f2bf(rintf(b * inv));
      o[w] = (unsigned)b0 | ((unsigned)b1 << 16);
    }
    uint4 ov; ov.x = o[0]; ov.y = o[1]; ov.z = o[2]; ov.w = o[3];
    Ar[c] = ov;
  }
  if (t < 64) {
    unsigned short v = 0;
    if (t < NOUT) {
      float xf = x[(size_t)m * IN_F + oidx[t]];
      float xc = fminf(fmaxf(xf, -upper), upper);
      v = f2bf((xf - xc) * inv);
    }
    A[(size_t)m * KPAD + IN_F + t] = v;
  }
}

// ---- main GEMM: 256x256, BK=64, 8 waves, 4-phase/K-tile interleaved schedule.
// LDS: [2 dbuf][2 M-half][128 rows][64 k] per matrix (64 KB each, 128 KB total).
// Per tile j: P1{rd av-lo:c0,bv:c0; stage A(j+1)L0,L2} P2{rd bv:c1,av-hi:c0; A(j+1)L1,L3}
//             P3{rd av-lo:c1; W(j+2)L0,L1} P4{rd av-hi:c1; W(j+2)L2,L3; vmcnt(4)}
// Hazards: bv reads of buf b retire in P2 -> W(j+2) into buf b legal from P3.
//          A(j+1) targets buf b^1 whose reads retired in tile j-1.  vmcnt in-order
//          retire: drain-to-4 at tile end completes A(j+1)+older, keeps W(j+2) flying.
__global__ __launch_bounds__(512, 2) void k_gemm(
    const unsigned short* __restrict__ A, const unsigned short* __restrict__ W,
    const float* __restrict__ bias, const unsigned* __restrict__ upper_bits,
    float* __restrict__ out) {
  __shared__ __attribute__((aligned(16))) unsigned short As[2][2][128][64];
  __shared__ __attribute__((aligned(16))) unsigned short Ws[2][2][128][64];

  const int t = threadIdx.x;

  // T1: bijective XCD swizzle (512 % 8 == 0); n-fastest within XCD chunk.
  const int wg = ((int)blockIdx.x & 7) * 64 + ((int)blockIdx.x >> 3);
  const int bm = (wg >> 4) * BM;
  const int bn = (wg & 15) * BN;

  const int lane = t & 63;
  const int wave = t >> 6;
  const int wm = (wave >> 2) * 128;
  const int wn = (wave & 3) * 64;
  const int lrow = lane & 15, lquad = lane >> 4;
  const int x7 = lrow & 7;
  const int hA = wm >> 7;
  const int hW = wn >> 7;
  const int rW0 = wn & 64;

  f32x4 acc[8][4] = {};

  // staging: thread t covers row t>>3 of each 64-row block, 16B slot t&7,
  // source k pre-swizzled so LDS stays linear (phys slot = logical ^ (row&7)).
  const int kswz = (((t & 7) ^ ((t >> 3) & 7)) * 8);
  const unsigned short* Ag = A + (size_t)(bm + (t >> 3)) * KPAD + kswz;
  const unsigned short* Wg = W + (size_t)(bn + (t >> 3)) * KPAD + kswz;

  const unsigned short* Asf = &As[0][0][0][0];
  const unsigned short* Wsf = &Ws[0][0][0][0];

#define STAGE_A(q, dbuf, kk) \
  GLDS16(Ag + (size_t)(q) * 64 * KPAD + (kk), (char*)As + (dbuf) * 32768 + (q) * 8192 + t * 16)
#define STAGE_W(q, dbuf, kk) \
  GLDS16(Wg + (size_t)(q) * 64 * KPAD + (kk), (char*)Ws + (dbuf) * 32768 + (q) * 8192 + t * 16)

#define LDA(b, ii, c) (*(const bf16x8*)(Asf + \
    (((b) * 2 + hA) * 128 + (ii) * 16 + lrow) * 64 + ((((c) * 4 + lquad) ^ x7) * 8)))
#define LDW(b, jj, c) (*(const bf16x8*)(Wsf + \
    (((b) * 2 + hW) * 128 + rW0 + (jj) * 16 + lrow) * 64 + ((((c) * 4 + lquad) ^ x7) * 8)))

#define PHASE_OPEN                                         \
  __builtin_amdgcn_s_barrier();                            \
  asm volatile("s_waitcnt lgkmcnt(0)" ::: "memory");       \
  __builtin_amdgcn_sched_barrier(0)

  // ---- prologue: A(0) all, W(0) all, W(1) all; wait first 8, keep W(1) flying
  STAGE_A(0, 0, 0); STAGE_A(1, 0, 0); STAGE_A(2, 0, 0); STAGE_A(3, 0, 0);
  STAGE_W(0, 0, 0); STAGE_W(1, 0, 0); STAGE_W(2, 0, 0); STAGE_W(3, 0, 0);
  STAGE_W(0, 1, BK); STAGE_W(1, 1, BK); STAGE_W(2, 1, BK); STAGE_W(3, 1, BK);
  asm volatile("s_waitcnt vmcnt(4)" ::: "memory");
  __builtin_amdgcn_s_barrier();

  for (int j = 0; j < KTILES; ++j) {
    const int b = j & 1;
    const int bA = b ^ 1;
    const int kA = (j < KTILES - 1 ? j + 1 : KTILES - 1) * BK;
    const int kW = (j < KTILES - 2 ? j + 2 : KTILES - 1) * BK;
    bf16x8 aLo[4], aHi[4], b0[4], b1[4];

    // ---- P1: av-lo c0 + bv c0 (8 rd); stage A(j+1) L0,L2
#pragma unroll
    for (int ii = 0; ii < 4; ++ii) aLo[ii] = LDA(b, ii, 0);
#pragma unroll
    for (int jj = 0; jj < 4; ++jj) b0[jj] = LDW(b, jj, 0);
    STAGE_A(0, bA, kA); STAGE_A(2, bA, kA);
    PHASE_OPEN;
    __builtin_amdgcn_s_setprio(1);
#pragma unroll
    for (int ii = 0; ii < 4; ++ii)
#pragma unroll
      for (int jj = 0; jj < 4; ++jj)
        acc[ii][jj] = __builtin_amdgcn_mfma_f32_16x16x32_bf16(aLo[ii], b0[jj], acc[ii][jj], 0, 0, 0);
    __builtin_amdgcn_s_setprio(0);
    __builtin_amdgcn_s_barrier();

    // ---- P2: bv c1 + av-hi c0 (8 rd); stage A(j+1) L1,L3
#pragma unroll
    for (int jj = 0; jj < 4; ++jj) b1[jj] = LDW(b, jj, 1);
#pragma unroll
    for (int ii = 0; ii < 4; ++ii) aHi[ii] = LDA(b, ii + 4, 0);
    STAGE_A(1, bA, kA); STAGE_A(3, bA, kA);
    PHASE_OPEN;
    __builtin_amdgcn_s_setprio(1);
#pragma unroll
    for (int ii = 0; ii < 4; ++ii)
#pragma unroll
      for (int jj = 0; jj < 4; ++jj)
        acc[ii + 4][jj] = __builtin_amdgcn_mfma_f32_16x16x32_bf16(aHi[ii], b0[jj], acc[ii + 4][jj], 0, 0, 0);
    __builtin_amdgcn_s_setprio(0);
    __builtin_amdgcn_s_barrier();

    // ---- P3: av-lo c1 (4 rd); stage W(j+2) L0,L1 (bv of buf b retired in P2)
#pragma unroll
    for (int ii = 0; ii < 4; ++ii) aLo[ii] = LDA(b, ii, 1);
    STAGE_W(0, b, kW); STAGE_W(1, b, kW);
    PHASE_OPEN;
    __builtin_amdgcn_s_setprio(1);
#pragma unroll
    for (int ii = 0; ii < 4; ++ii)
#pragma unroll
      for (int jj = 0; jj < 4; ++jj)
        acc[ii][jj] = __builtin_amdgcn_mfma_f32_16x16x32_bf16(aLo[ii], b1[jj], acc[ii][jj], 0, 0, 0);
    __builtin_amdgcn_s_setprio(0);
    __builtin_amdgcn_s_barrier();

    // ---- P4: av-hi c1 (4 rd); stage W(j+2) L2,L3; counted drain at tile end
#pragma unroll
    for (int ii = 0; ii < 4; ++ii) aHi[ii] = LDA(b, ii + 4, 1);
    STAGE_W(2, b, kW); STAGE_W(3, b, kW);
    PHASE_OPEN;
    __builtin_amdgcn_s_setprio(1);
#pragma unroll
    for (int ii = 0; ii < 4; ++ii)
#pragma unroll
      for (int jj = 0; jj < 4; ++jj)
        acc[ii + 4][jj] = __builtin_amdgcn_mfma_f32_16x16x32_bf16(aHi[ii], b1[jj], acc[ii + 4][jj], 0, 0, 0);
    __builtin_amdgcn_s_setprio(0);
    asm volatile("s_waitcnt vmcnt(4)" ::: "memory");
    __builtin_amdgcn_s_barrier();
  }
  asm volatile("s_waitcnt vmcnt(0)" ::: "memory");
#undef STAGE_A
#undef STAGE_W
#undef LDA
#undef LDW
#undef PHASE_OPEN

  const float scale = fmaxf(__uint_as_float(*upper_bits), 1e-5f) * (1.0f / 127.0f);
#pragma unroll
  for (int ii = 0; ii < 8; ++ii) {
    const int row = bm + wm + ii * 16 + lquad * 4;  // C/D: row = quad*4 + reg
#pragma unroll
    for (int jj = 0; jj < 4; ++jj) {
      const int col = bn + wn + jj * 16 + lrow;     // C/D: col = lane & 15
      const float bs = bias[col];
#pragma unroll
      for (int r = 0; r < 4; ++r)
        out[(size_t)(row + r) * OUT_F + col] = scale * acc[ii][jj][r] + bs;
    }
  }
}

extern "C" void kernel_launch(void* const* d_in, const int* in_sizes, int n_in,
                              void* d_out, int out_size, void* d_ws, size_t ws_size,
                              hipStream_t stream) {
  (void)in_sizes; (void)n_in; (void)out_size; (void)ws_size;
  const float* x    = (const float*)d_in[0];  // fp32 [4,2048,4096]
  const float* w    = (const float*)d_in[1];  // fp32 [4096,4096]
  const float* B    = (const float*)d_in[2];  // fp32 [4096,40]
  const float* bias = (const float*)d_in[3];  // fp32 [1,4096]
  const int* oidx   = (const int*)d_in[4];    // int32 [40]
  float* out = (float*)d_out;                 // fp32 [4,2048,4096]

  char* ws = (char*)d_ws;
  unsigned* upper = (unsigned*)ws;                     // 4 B atomic slot
  unsigned short* Ap = (unsigned short*)(ws + 65536);  // 8192*4160*2 = 68 MB
  unsigned short* Wp = Ap + (size_t)M_TOT * KPAD;      // 4096*4160*2 = 34 MB

  hipMemsetAsync(upper, 0, 4, stream);
  k_absmax_prepw<<<ABS_BLOCKS + OUT_F, 256, 0, stream>>>(
      (const float4*)x, oidx, upper, w, B, Wp);
  k_prep_a<<<M_TOT, 256, 0, stream>>>(x, oidx, upper, Ap);
  k_gemm<<<(M_TOT / BM) * (OUT_F / BN), 512, 0, stream>>>(Ap, Wp, bias, upper, out);
}

// Round 3
// 529.237 us; speedup vs baseline: 1.3438x; 1.3438x over previous
//
#include <hip/hip_runtime.h>
#include <hip/hip_bf16.h>
#include <stdint.h>

#define IN_F 4096
#define OUT_F 4096
#define NOUT 40
#define KPAD 4160   // 4096 + 64 (40 outlier cols + 24 zero pad) = 65 * 64
#define M_TOT 8192  // 4*2048

#define BM 256
#define BN 256
#define BK 64
#define KTILES 65   // KPAD / BK
#define ABS_BLOCKS 1024

typedef float f32x4 __attribute__((ext_vector_type(4)));
typedef __bf16 bf16x8 __attribute__((ext_vector_type(8)));

typedef __attribute__((address_space(1))) void GV;
typedef __attribute__((address_space(3))) void LV;
#define GLDS16(gp, lp) \
  __builtin_amdgcn_global_load_lds((GV*)(gp), (LV*)(lp), 16, 0, 0)

__device__ __forceinline__ unsigned short f2bf(float f) {
  unsigned u = __float_as_uint(f);
  u += 0x7FFFu + ((u >> 16) & 1u);
  return (unsigned short)(u >> 16);
}

// ---- fused: masked abs-max partials (no atomics)  ||  W' = [W | B | 0] prep ----
// blocks [0, ABS_BLOCKS): per-block masked abs-max -> partial[blk] (plain store).
// blocks [ABS_BLOCKS, ABS_BLOCKS+OUT_F): prep_w.
__global__ void k_absmax_prepw(const float4* __restrict__ x4,
                               const int* __restrict__ oidx,
                               float* __restrict__ partial,
                               const float* __restrict__ w,
                               const float* __restrict__ Bm,
                               unsigned short* __restrict__ W) {
  __shared__ unsigned bits[128];
  __shared__ float wmax[4];
  const int t = threadIdx.x;
  if ((int)blockIdx.x < ABS_BLOCKS) {
    if (t < 128) bits[t] = 0;
    __syncthreads();
    if (t < NOUT) {
      int c = oidx[t];
      atomicOr(&bits[c >> 5], 1u << (c & 31));
    }
    __syncthreads();
    const int n4 = M_TOT * IN_F / 4;
    float m = 0.f;
    const int stride = ABS_BLOCKS * 256;
    for (int i = blockIdx.x * 256 + t; i < n4; i += stride) {
      float4 u = x4[i];
      unsigned wb = bits[(i & 1023) >> 3];  // word for columns (i*4..i*4+3) % 4096
      int sh = (i & 7) * 4;
      m = fmaxf(m, ((wb >> (sh + 0)) & 1) ? 0.f : fabsf(u.x));
      m = fmaxf(m, ((wb >> (sh + 1)) & 1) ? 0.f : fabsf(u.y));
      m = fmaxf(m, ((wb >> (sh + 2)) & 1) ? 0.f : fabsf(u.z));
      m = fmaxf(m, ((wb >> (sh + 3)) & 1) ? 0.f : fabsf(u.w));
    }
#pragma unroll
    for (int off = 32; off; off >>= 1) m = fmaxf(m, __shfl_down(m, off, 64));
    if ((t & 63) == 0) wmax[t >> 6] = m;
    __syncthreads();
    if (t == 0)
      partial[blockIdx.x] =
          fmaxf(fmaxf(wmax[0], wmax[1]), fmaxf(wmax[2], wmax[3]));
  } else {
    const int o = (int)blockIdx.x - ABS_BLOCKS;
    const float4* wr = (const float4*)(w + (size_t)o * IN_F);
    uint4* Wr = (uint4*)(W + (size_t)o * KPAD);
#pragma unroll
    for (int rep = 0; rep < 2; ++rep) {
      const int c = t + rep * 256;
      float4 u0 = wr[2 * c];
      float4 u1 = wr[2 * c + 1];
      uint4 ov;
      ov.x = (unsigned)f2bf(u0.x) | ((unsigned)f2bf(u0.y) << 16);
      ov.y = (unsigned)f2bf(u0.z) | ((unsigned)f2bf(u0.w) << 16);
      ov.z = (unsigned)f2bf(u1.x) | ((unsigned)f2bf(u1.y) << 16);
      ov.w = (unsigned)f2bf(u1.z) | ((unsigned)f2bf(u1.w) << 16);
      Wr[c] = ov;
    }
    if (t < 64)
      W[(size_t)o * KPAD + IN_F + t] =
          (t < NOUT) ? f2bf(Bm[(size_t)o * NOUT + t]) : (unsigned short)0;
  }
}

// ---- reduce 1024 partials -> upper (single block, no contention) ----
__global__ void k_finalize(const float* __restrict__ partial,
                           unsigned* __restrict__ out) {
  __shared__ float wmax[4];
  const int t = threadIdx.x;
  float m = 0.f;
  for (int i = t; i < ABS_BLOCKS; i += 256) m = fmaxf(m, partial[i]);
#pragma unroll
  for (int off = 32; off; off >>= 1) m = fmaxf(m, __shfl_down(m, off, 64));
  if ((t & 63) == 0) wmax[t >> 6] = m;
  __syncthreads();
  if (t == 0)
    *out = __float_as_uint(
        fmaxf(fmaxf(wmax[0], wmax[1]), fmaxf(wmax[2], wmax[3])));
}

// ---- A' = [rint(clip(x)*127/upper) | (x - clip(x))*127/upper on outlier cols | 0] ----
__global__ void k_prep_a(const float* __restrict__ x,
                         const int* __restrict__ oidx,
                         const unsigned* __restrict__ upper_bits,
                         unsigned short* __restrict__ A) {
  const int m = blockIdx.x;
  const int t = threadIdx.x;
  const float upper = __uint_as_float(*upper_bits);
  const float inv = 127.0f / fmaxf(upper, 1e-5f);
  const float4* xr = (const float4*)(x + (size_t)m * IN_F);
  uint4* Ar = (uint4*)(A + (size_t)m * KPAD);
#pragma unroll
  for (int rep = 0; rep < 2; ++rep) {
    const int c = t + rep * 256;
    float4 u0 = xr[2 * c];
    float4 u1 = xr[2 * c + 1];
    float f[8] = {u0.x, u0.y, u0.z, u0.w, u1.x, u1.y, u1.z, u1.w};
    unsigned o[4];
#pragma unroll
    for (int w = 0; w < 4; ++w) {
      float a = fminf(fmaxf(f[2 * w], -upper), upper);
      float b = fminf(fmaxf(f[2 * w + 1], -upper), upper);
      unsigned short b0 = f2bf(rintf(a * inv));
      unsigned short b1 = f2bf(rintf(b * inv));
      o[w] = (unsigned)b0 | ((unsigned)b1 << 16);
    }
    uint4 ov; ov.x = o[0]; ov.y = o[1]; ov.z = o[2]; ov.w = o[3];
    Ar[c] = ov;
  }
  if (t < 64) {
    unsigned short v = 0;
    if (t < NOUT) {
      float xf = x[(size_t)m * IN_F + oidx[t]];
      float xc = fminf(fmaxf(xf, -upper), upper);
      v = f2bf((xf - xc) * inv);
    }
    A[(size_t)m * KPAD + IN_F + t] = v;
  }
}

// ---- main GEMM: 256x256 tile, BK=64, 8 waves, double-buffered LDS,
//      counted s_waitcnt vmcnt(8) (never drained in steady state), raw barriers,
//      3-bit XOR LDS swizzle (slot ^= row&7) via pre-swizzled global src.
//      (R1 structure: 275 us / 45% MfmaUtil measured; R2 4-phase split regressed.)
__global__ __launch_bounds__(512, 2) void k_gemm(
    const unsigned short* __restrict__ A, const unsigned short* __restrict__ W,
    const float* __restrict__ bias, const unsigned* __restrict__ upper_bits,
    float* __restrict__ out) {
  __shared__ __attribute__((aligned(16))) unsigned short As[2][BM * BK];
  __shared__ __attribute__((aligned(16))) unsigned short Ws[2][BN * BK];

  const int t = threadIdx.x;

  // T1: bijective XCD swizzle (512 % 8 == 0); n-fastest within XCD chunk.
  const int wg = ((int)blockIdx.x & 7) * 64 + ((int)blockIdx.x >> 3);
  const int bm = (wg >> 4) * BM;   // 32 m-tiles
  const int bn = (wg & 15) * BN;   // 16 n-tiles

  const int lane = t & 63;
  const int wave = t >> 6;
  const int wm = (wave >> 2) * 128;
  const int wn = (wave & 3) * 64;
  const int lrow = lane & 15, lquad = lane >> 4;

  f32x4 acc[8][4] = {};

  // staging: thread t writes LDS row t>>3, 16B-slot t&7; source k pre-swizzled
  // (phys slot = logical ^ (row&7)) so LDS dest stays linear.
  const int kswz = (((t & 7) ^ ((t >> 3) & 7)) * 8);
  const unsigned short* Ag = A + (size_t)(bm + (t >> 3)) * KPAD + kswz;
  const unsigned short* Wg = W + (size_t)(bn + (t >> 3)) * KPAD + kswz;
  char* ldsA0 = (char*)&As[0][0] + t * 16;
  char* ldsA1 = (char*)&As[1][0] + t * 16;
  char* ldsW0 = (char*)&Ws[0][0] + t * 16;
  char* ldsW1 = (char*)&Ws[1][0] + t * 16;
  const size_t rstep = (size_t)64 * KPAD;

#define STAGE_TILE(lA, lW, k0)                      \
  do {                                              \
    GLDS16(Ag + (k0), (lA));                        \
    GLDS16(Ag + (k0) + rstep, (lA) + 8192);         \
    GLDS16(Ag + (k0) + 2 * rstep, (lA) + 16384);    \
    GLDS16(Ag + (k0) + 3 * rstep, (lA) + 24576);    \
    GLDS16(Wg + (k0), (lW));                        \
    GLDS16(Wg + (k0) + rstep, (lW) + 8192);         \
    GLDS16(Wg + (k0) + 2 * rstep, (lW) + 16384);    \
    GLDS16(Wg + (k0) + 3 * rstep, (lW) + 24576);    \
  } while (0)

  // fragment-read swizzle: physical slot = logical slot ^ (row&7)
  const int x7 = lrow & 7;
  const int s0 = ((lquad) ^ x7) * 8;       // k-chunk 0
  const int s1 = ((4 + lquad) ^ x7) * 8;   // k-chunk 1

  // prologue: stage tiles 0,1; wait tile 0 only (tile 1 stays in flight)
  STAGE_TILE(ldsA0, ldsW0, 0);
  STAGE_TILE(ldsA1, ldsW1, BK);
  asm volatile("s_waitcnt vmcnt(8)\n\ts_barrier" ::: "memory");

  for (int j = 0; j < KTILES; ++j) {
    const int b = j & 1;
    const unsigned short* Ab = b ? &As[1][0] : &As[0][0];
    const unsigned short* Wb = b ? &Ws[1][0] : &Ws[0][0];

    bf16x8 av[8][2], bv[4][2];
#pragma unroll
    for (int c = 0; c < 2; ++c) {
      const int sc = c ? s1 : s0;
#pragma unroll
      for (int jj = 0; jj < 4; ++jj)
        bv[jj][c] = *(const bf16x8*)(Wb + (wn + jj * 16 + lrow) * BK + sc);
#pragma unroll
      for (int ii = 0; ii < 8; ++ii)
        av[ii][c] = *(const bf16x8*)(Ab + (wm + ii * 16 + lrow) * BK + sc);
    }

    if (j < KTILES - 2) {
      // all reads of buf b done -> free it, then prefetch tile j+2 into it
      asm volatile("s_waitcnt lgkmcnt(0)\n\ts_barrier" ::: "memory");
      char* lA = b ? ldsA1 : ldsA0;
      char* lW = b ? ldsW1 : ldsW0;
      STAGE_TILE(lA, lW, (j + 2) * BK);
    }

    __builtin_amdgcn_s_setprio(1);
#pragma unroll
    for (int c = 0; c < 2; ++c)
#pragma unroll
      for (int ii = 0; ii < 8; ++ii)
#pragma unroll
        for (int jj = 0; jj < 4; ++jj)
          acc[ii][jj] = __builtin_amdgcn_mfma_f32_16x16x32_bf16(
              av[ii][c], bv[jj][c], acc[ii][jj], 0, 0, 0);
    __builtin_amdgcn_s_setprio(0);

    if (j < KTILES - 2) {
      // tile j+1's 8 loads are the oldest outstanding; tile j+2's 8 fly on
      asm volatile("s_waitcnt vmcnt(8)\n\ts_barrier" ::: "memory");
    } else if (j == KTILES - 2) {
      asm volatile("s_waitcnt vmcnt(0)\n\ts_barrier" ::: "memory");
    }
  }
#undef STAGE_TILE

  const float scale = fmaxf(__uint_as_float(*upper_bits), 1e-5f) * (1.0f / 127.0f);
#pragma unroll
  for (int ii = 0; ii < 8; ++ii) {
    const int row = bm + wm + ii * 16 + lquad * 4;  // C/D: row = quad*4 + reg
#pragma unroll
    for (int jj = 0; jj < 4; ++jj) {
      const int col = bn + wn + jj * 16 + lrow;     // C/D: col = lane & 15
      const float bs = bias[col];
#pragma unroll
      for (int r = 0; r < 4; ++r)
        out[(size_t)(row + r) * OUT_F + col] = scale * acc[ii][jj][r] + bs;
    }
  }
}

extern "C" void kernel_launch(void* const* d_in, const int* in_sizes, int n_in,
                              void* d_out, int out_size, void* d_ws, size_t ws_size,
                              hipStream_t stream) {
  (void)in_sizes; (void)n_in; (void)out_size; (void)ws_size;
  const float* x    = (const float*)d_in[0];  // fp32 [4,2048,4096]
  const float* w    = (const float*)d_in[1];  // fp32 [4096,4096]
  const float* B    = (const float*)d_in[2];  // fp32 [4096,40]
  const float* bias = (const float*)d_in[3];  // fp32 [1,4096]
  const int* oidx   = (const int*)d_in[4];    // int32 [40]
  float* out = (float*)d_out;                 // fp32 [4,2048,4096]

  char* ws = (char*)d_ws;
  unsigned* upper = (unsigned*)ws;                     // 4 B result slot
  float* partial = (float*)(ws + 256);                 // 1024 floats
  unsigned short* Ap = (unsigned short*)(ws + 65536);  // 8192*4160*2 = 68 MB
  unsigned short* Wp = Ap + (size_t)M_TOT * KPAD;      // 4096*4160*2 = 34 MB

  k_absmax_prepw<<<ABS_BLOCKS + OUT_F, 256, 0, stream>>>(
      (const float4*)x, oidx, partial, w, B, Wp);
  k_finalize<<<1, 256, 0, stream>>>(partial, upper);
  k_prep_a<<<M_TOT, 256, 0, stream>>>(x, oidx, upper, Ap);
  k_gemm<<<(M_TOT / BM) * (OUT_F / BN), 512, 0, stream>>>(Ap, Wp, bias, upper, out);
}

// Round 4
// 528.257 us; speedup vs baseline: 1.3463x; 1.0019x over previous
//
#include <hip/hip_runtime.h>
#include <hip/hip_bf16.h>
#include <stdint.h>

#define IN_F 4096
#define OUT_F 4096
#define NOUT 40
#define KPAD 4160   // 4096 + 64 (40 outlier cols + 24 zero pad) = 65 * 64
#define M_TOT 8192  // 4*2048

#define BM 256
#define BN 256
#define BK 64
#define KTILES 65   // KPAD / BK
#define ABS_BLOCKS 2048
#define PA_BLOCKS 2048

typedef float f32x4 __attribute__((ext_vector_type(4)));
typedef __bf16 bf16x8 __attribute__((ext_vector_type(8)));

typedef __attribute__((address_space(1))) void GV;
typedef __attribute__((address_space(3))) void LV;
#define GLDS16(gp, lp) \
  __builtin_amdgcn_global_load_lds((GV*)(gp), (LV*)(lp), 16, 0, 0)

__device__ __forceinline__ unsigned short f2bf(float f) {
  unsigned u = __float_as_uint(f);
  u += 0x7FFFu + ((u >> 16) & 1u);
  return (unsigned short)(u >> 16);
}

// ---- fused: masked abs-max partials (no atomics)  ||  W' = [W | B | 0] prep ----
// blocks [0, ABS_BLOCKS): per-block masked abs-max -> partial[blk] (plain store).
// blocks [ABS_BLOCKS, ABS_BLOCKS+OUT_F): prep_w.
__global__ void k_absmax_prepw(const float4* __restrict__ x4,
                               const int* __restrict__ oidx,
                               float* __restrict__ partial,
                               const float* __restrict__ w,
                               const float* __restrict__ Bm,
                               unsigned short* __restrict__ W) {
  __shared__ unsigned bits[128];
  __shared__ float wmax[4];
  const int t = threadIdx.x;
  if ((int)blockIdx.x < ABS_BLOCKS) {
    if (t < 128) bits[t] = 0;
    __syncthreads();
    if (t < NOUT) {
      int c = oidx[t];
      atomicOr(&bits[c >> 5], 1u << (c & 31));
    }
    __syncthreads();
    const int n4 = M_TOT * IN_F / 4;
    float m = 0.f;
    const int stride = ABS_BLOCKS * 256;
    for (int i = blockIdx.x * 256 + t; i < n4; i += stride) {
      float4 u = x4[i];
      unsigned wb = bits[(i & 1023) >> 3];  // word for columns (i*4..i*4+3) % 4096
      int sh = (i & 7) * 4;
      m = fmaxf(m, ((wb >> (sh + 0)) & 1) ? 0.f : fabsf(u.x));
      m = fmaxf(m, ((wb >> (sh + 1)) & 1) ? 0.f : fabsf(u.y));
      m = fmaxf(m, ((wb >> (sh + 2)) & 1) ? 0.f : fabsf(u.z));
      m = fmaxf(m, ((wb >> (sh + 3)) & 1) ? 0.f : fabsf(u.w));
    }
#pragma unroll
    for (int off = 32; off; off >>= 1) m = fmaxf(m, __shfl_down(m, off, 64));
    if ((t & 63) == 0) wmax[t >> 6] = m;
    __syncthreads();
    if (t == 0)
      partial[blockIdx.x] =
          fmaxf(fmaxf(wmax[0], wmax[1]), fmaxf(wmax[2], wmax[3]));
  } else {
    const int o = (int)blockIdx.x - ABS_BLOCKS;
    const float4* wr = (const float4*)(w + (size_t)o * IN_F);
    uint4* Wr = (uint4*)(W + (size_t)o * KPAD);
#pragma unroll
    for (int rep = 0; rep < 2; ++rep) {
      const int c = t + rep * 256;
      float4 u0 = wr[2 * c];
      float4 u1 = wr[2 * c + 1];
      uint4 ov;
      ov.x = (unsigned)f2bf(u0.x) | ((unsigned)f2bf(u0.y) << 16);
      ov.y = (unsigned)f2bf(u0.z) | ((unsigned)f2bf(u0.w) << 16);
      ov.z = (unsigned)f2bf(u1.x) | ((unsigned)f2bf(u1.y) << 16);
      ov.w = (unsigned)f2bf(u1.z) | ((unsigned)f2bf(u1.w) << 16);
      Wr[c] = ov;
    }
    if (t < 64)
      W[(size_t)o * KPAD + IN_F + t] =
          (t < NOUT) ? f2bf(Bm[(size_t)o * NOUT + t]) : (unsigned short)0;
  }
}

// ---- prep_a with in-block finalize: reduce partials -> upper, then
//      A' = [rint(clip(x)*127/upper) | (x-clip(x))*127/upper on outlier cols | 0]
//      2048 blocks x 4 rows each (grid-stride over 8192 rows).
__global__ void k_prep_a(const float* __restrict__ x,
                         const int* __restrict__ oidx,
                         const float* __restrict__ partial,
                         unsigned* __restrict__ upper_out,
                         unsigned short* __restrict__ A) {
  __shared__ float wmax[4];
  __shared__ float s_upper;
  const int t = threadIdx.x;
  // prologue: exact (order-independent) max over 2048 partials
  float m = 0.f;
#pragma unroll
  for (int r = 0; r < ABS_BLOCKS / 256; ++r)
    m = fmaxf(m, partial[t + r * 256]);
#pragma unroll
  for (int off = 32; off; off >>= 1) m = fmaxf(m, __shfl_down(m, off, 64));
  if ((t & 63) == 0) wmax[t >> 6] = m;
  __syncthreads();
  if (t == 0) {
    float u = fmaxf(fmaxf(wmax[0], wmax[1]), fmaxf(wmax[2], wmax[3]));
    s_upper = u;
    if (blockIdx.x == 0) *upper_out = __float_as_uint(u);
  }
  __syncthreads();
  const float upper = s_upper;
  const float inv = 127.0f / fmaxf(upper, 1e-5f);

  for (int r = 0; r < M_TOT / PA_BLOCKS; ++r) {
    const int mrow = (int)blockIdx.x + r * PA_BLOCKS;
    const float4* xr = (const float4*)(x + (size_t)mrow * IN_F);
    uint4* Ar = (uint4*)(A + (size_t)mrow * KPAD);
#pragma unroll
    for (int rep = 0; rep < 2; ++rep) {
      const int c = t + rep * 256;
      float4 u0 = xr[2 * c];
      float4 u1 = xr[2 * c + 1];
      float f[8] = {u0.x, u0.y, u0.z, u0.w, u1.x, u1.y, u1.z, u1.w};
      unsigned o[4];
#pragma unroll
      for (int w = 0; w < 4; ++w) {
        float a = fminf(fmaxf(f[2 * w], -upper), upper);
        float b = fminf(fmaxf(f[2 * w + 1], -upper), upper);
        unsigned short b0 = f2bf(rintf(a * inv));
        unsigned short b1 = f2bf(rintf(b * inv));
        o[w] = (unsigned)b0 | ((unsigned)b1 << 16);
      }
      uint4 ov; ov.x = o[0]; ov.y = o[1]; ov.z = o[2]; ov.w = o[3];
      Ar[c] = ov;
    }
    if (t < 64) {
      unsigned short v = 0;
      if (t < NOUT) {
        float xf = x[(size_t)mrow * IN_F + oidx[t]];
        float xc = fminf(fmaxf(xf, -upper), upper);
        v = f2bf((xf - xc) * inv);
      }
      A[(size_t)mrow * KPAD + IN_F + t] = v;
    }
  }
}

// ---- main GEMM: 256x256 tile, BK=64, 8 waves, double-buffered LDS,
//      counted s_waitcnt vmcnt(8) (never drained in steady state), raw barriers,
//      3-bit XOR LDS swizzle (slot ^= row&7) via pre-swizzled global src.
//      (R1/R3 structure: 273 us / 45% MfmaUtil measured — FROZEN as control.)
__global__ __launch_bounds__(512, 2) void k_gemm(
    const unsigned short* __restrict__ A, const unsigned short* __restrict__ W,
    const float* __restrict__ bias, const unsigned* __restrict__ upper_bits,
    float* __restrict__ out) {
  __shared__ __attribute__((aligned(16))) unsigned short As[2][BM * BK];
  __shared__ __attribute__((aligned(16))) unsigned short Ws[2][BN * BK];

  const int t = threadIdx.x;

  // T1: bijective XCD swizzle (512 % 8 == 0); n-fastest within XCD chunk.
  const int wg = ((int)blockIdx.x & 7) * 64 + ((int)blockIdx.x >> 3);
  const int bm = (wg >> 4) * BM;   // 32 m-tiles
  const int bn = (wg & 15) * BN;   // 16 n-tiles

  const int lane = t & 63;
  const int wave = t >> 6;
  const int wm = (wave >> 2) * 128;
  const int wn = (wave & 3) * 64;
  const int lrow = lane & 15, lquad = lane >> 4;

  f32x4 acc[8][4] = {};

  // staging: thread t writes LDS row t>>3, 16B-slot t&7; source k pre-swizzled
  // (phys slot = logical ^ (row&7)) so LDS dest stays linear.
  const int kswz = (((t & 7) ^ ((t >> 3) & 7)) * 8);
  const unsigned short* Ag = A + (size_t)(bm + (t >> 3)) * KPAD + kswz;
  const unsigned short* Wg = W + (size_t)(bn + (t >> 3)) * KPAD + kswz;
  char* ldsA0 = (char*)&As[0][0] + t * 16;
  char* ldsA1 = (char*)&As[1][0] + t * 16;
  char* ldsW0 = (char*)&Ws[0][0] + t * 16;
  char* ldsW1 = (char*)&Ws[1][0] + t * 16;
  const size_t rstep = (size_t)64 * KPAD;

#define STAGE_TILE(lA, lW, k0)                      \
  do {                                              \
    GLDS16(Ag + (k0), (lA));                        \
    GLDS16(Ag + (k0) + rstep, (lA) + 8192);         \
    GLDS16(Ag + (k0) + 2 * rstep, (lA) + 16384);    \
    GLDS16(Ag + (k0) + 3 * rstep, (lA) + 24576);    \
    GLDS16(Wg + (k0), (lW));                        \
    GLDS16(Wg + (k0) + rstep, (lW) + 8192);         \
    GLDS16(Wg + (k0) + 2 * rstep, (lW) + 16384);    \
    GLDS16(Wg + (k0) + 3 * rstep, (lW) + 24576);    \
  } while (0)

  // fragment-read swizzle: physical slot = logical slot ^ (row&7)
  const int x7 = lrow & 7;
  const int s0 = ((lquad) ^ x7) * 8;       // k-chunk 0
  const int s1 = ((4 + lquad) ^ x7) * 8;   // k-chunk 1

  // prologue: stage tiles 0,1; wait tile 0 only (tile 1 stays in flight)
  STAGE_TILE(ldsA0, ldsW0, 0);
  STAGE_TILE(ldsA1, ldsW1, BK);
  asm volatile("s_waitcnt vmcnt(8)\n\ts_barrier" ::: "memory");

  for (int j = 0; j < KTILES; ++j) {
    const int b = j & 1;
    const unsigned short* Ab = b ? &As[1][0] : &As[0][0];
    const unsigned short* Wb = b ? &Ws[1][0] : &Ws[0][0];

    bf16x8 av[8][2], bv[4][2];
#pragma unroll
    for (int c = 0; c < 2; ++c) {
      const int sc = c ? s1 : s0;
#pragma unroll
      for (int jj = 0; jj < 4; ++jj)
        bv[jj][c] = *(const bf16x8*)(Wb + (wn + jj * 16 + lrow) * BK + sc);
#pragma unroll
      for (int ii = 0; ii < 8; ++ii)
        av[ii][c] = *(const bf16x8*)(Ab + (wm + ii * 16 + lrow) * BK + sc);
    }

    if (j < KTILES - 2) {
      // all reads of buf b done -> free it, then prefetch tile j+2 into it
      asm volatile("s_waitcnt lgkmcnt(0)\n\ts_barrier" ::: "memory");
      char* lA = b ? ldsA1 : ldsA0;
      char* lW = b ? ldsW1 : ldsW0;
      STAGE_TILE(lA, lW, (j + 2) * BK);
    }

    __builtin_amdgcn_s_setprio(1);
#pragma unroll
    for (int c = 0; c < 2; ++c)
#pragma unroll
      for (int ii = 0; ii < 8; ++ii)
#pragma unroll
        for (int jj = 0; jj < 4; ++jj)
          acc[ii][jj] = __builtin_amdgcn_mfma_f32_16x16x32_bf16(
              av[ii][c], bv[jj][c], acc[ii][jj], 0, 0, 0);
    __builtin_amdgcn_s_setprio(0);

    if (j < KTILES - 2) {
      // tile j+1's 8 loads are the oldest outstanding; tile j+2's 8 fly on
      asm volatile("s_waitcnt vmcnt(8)\n\ts_barrier" ::: "memory");
    } else if (j == KTILES - 2) {
      asm volatile("s_waitcnt vmcnt(0)\n\ts_barrier" ::: "memory");
    }
  }
#undef STAGE_TILE

  const float scale = fmaxf(__uint_as_float(*upper_bits), 1e-5f) * (1.0f / 127.0f);
#pragma unroll
  for (int ii = 0; ii < 8; ++ii) {
    const int row = bm + wm + ii * 16 + lquad * 4;  // C/D: row = quad*4 + reg
#pragma unroll
    for (int jj = 0; jj < 4; ++jj) {
      const int col = bn + wn + jj * 16 + lrow;     // C/D: col = lane & 15
      const float bs = bias[col];
#pragma unroll
      for (int r = 0; r < 4; ++r)
        out[(size_t)(row + r) * OUT_F + col] = scale * acc[ii][jj][r] + bs;
    }
  }
}

extern "C" void kernel_launch(void* const* d_in, const int* in_sizes, int n_in,
                              void* d_out, int out_size, void* d_ws, size_t ws_size,
                              hipStream_t stream) {
  (void)in_sizes; (void)n_in; (void)out_size; (void)ws_size;
  const float* x    = (const float*)d_in[0];  // fp32 [4,2048,4096]
  const float* w    = (const float*)d_in[1];  // fp32 [4096,4096]
  const float* B    = (const float*)d_in[2];  // fp32 [4096,40]
  const float* bias = (const float*)d_in[3];  // fp32 [1,4096]
  const int* oidx   = (const int*)d_in[4];    // int32 [40]
  float* out = (float*)d_out;                 // fp32 [4,2048,4096]

  char* ws = (char*)d_ws;
  unsigned* upper = (unsigned*)ws;                     // 4 B result slot
  float* partial = (float*)(ws + 256);                 // 2048 floats
  unsigned short* Ap = (unsigned short*)(ws + 65536);  // 8192*4160*2 = 68 MB
  unsigned short* Wp = Ap + (size_t)M_TOT * KPAD;      // 4096*4160*2 = 34 MB

  k_absmax_prepw<<<ABS_BLOCKS + OUT_F, 256, 0, stream>>>(
      (const float4*)x, oidx, partial, w, B, Wp);
  k_prep_a<<<PA_BLOCKS, 256, 0, stream>>>(x, oidx, partial, upper, Ap);
  k_gemm<<<(M_TOT / BM) * (OUT_F / BN), 512, 0, stream>>>(Ap, Wp, bias, upper, out);
}